// Round 3
// baseline (440.586 us; speedup 1.0000x reference)
//
#include <hip/hip_runtime.h>
#include <hip/hip_bf16.h>
#include <cstdint>
#include <cstddef>

#define DEVI __device__ __forceinline__

typedef unsigned short u16;
using frag_ab = __attribute__((ext_vector_type(8))) short;   // 8 bf16 (4 VGPRs)
using f32x4   = __attribute__((ext_vector_type(4))) float;   // mfma acc

constexpr int HW = 16384;   // 128*128 spatial
constexpr int NC = 256;     // channels (Cin = Cout = 256)

DEVI u16 bf16bits(float f) {
    union { float f; uint32_t u; } cv; cv.f = f;
    uint32_t u = cv.u;
    u += 0x7fffu + ((u >> 16) & 1u);   // RNE
    return (u16)(u >> 16);
}

DEVI void gload16(const void* g, void* l) {
    __builtin_amdgcn_global_load_lds(
        (const __attribute__((address_space(1))) uint32_t*)g,
        (__attribute__((address_space(3))) uint32_t*)l, 16, 0, 0);
}

// LDS slab layout: [row][64B k-slice]; 16B slot s stored at phys slot s ^ (row&3) ^ ((row>>2)&3)
// -> ds_read_b128 frag loads are 2-way bank-aliased (free, m136); staging stays gload16-linear
// (pre-swizzled global source, m173).
DEVI frag_ab read_frag(const u16* slab, int row, int l4) {
    const int phys = (l4 ^ row ^ (row >> 2)) & 3;
    return *(const frag_ab*)((const char*)slab + row * 64 + phys * 16);
}

// ---------------- pass 1: x partial stats + transpose to xt[b][p][c] bf16 ----------------
// each thread owns a 4ch x 4px block: float4 loads, in-register transpose, ds_write_b64 (4-way max)
__global__ __launch_bounds__(256) void transpose_stats_kernel(
    const float* __restrict__ x, u16* __restrict__ xt,
    float* __restrict__ ps, float* __restrict__ pq)
{
    constexpr int PADW = 68;                       // row pitch in u16 (136B): breaks pow2 strides
    __shared__ __align__(16) u16 tile[64 * PADW];  // [px][ch]
    const int b = blockIdx.z, c0 = blockIdx.y * 64, p0 = blockIdx.x * 64;
    const int pblk = blockIdx.x;                   // 64-pixel slice id, 0..255
    const int t = threadIdx.x;
    const int lane = t & 63, w = t >> 6;
    const int pq_ = lane & 15, cq = lane >> 4;     // pixel-quad 0..15, ch-quad-in-wave 0..3
    const int quad = w * 4 + cq;                   // ch-quad 0..15
    const float* xb = x + ((size_t)b * NC + c0) * HW + p0;

    float va[4][4];                                // [j=ch][i=px]
    #pragma unroll
    for (int j = 0; j < 4; ++j) {
        const float4 v = *(const float4*)(xb + (size_t)(quad * 4 + j) * HW + pq_ * 4);
        va[j][0] = v.x; va[j][1] = v.y; va[j][2] = v.z; va[j][3] = v.w;
        float s1 = v.x + v.y + v.z + v.w;
        float s2 = v.x*v.x + v.y*v.y + v.z*v.z + v.w*v.w;
        #pragma unroll
        for (int d = 1; d < 16; d <<= 1) {
            s1 += __shfl_xor(s1, d, 64);
            s2 += __shfl_xor(s2, d, 64);
        }
        if (pq_ == 0) {
            const int ch = quad * 4 + j;
            ps[((size_t)b * 256 + pblk) * NC + c0 + ch] = s1;
            pq[((size_t)b * 256 + pblk) * NC + c0 + ch] = s2;
        }
    }
    #pragma unroll
    for (int i = 0; i < 4; ++i) {                  // px within quad
        alignas(8) u16 pk[4];
        #pragma unroll
        for (int j = 0; j < 4; ++j) pk[j] = bf16bits(va[j][i]);
        *(uint2*)&tile[(pq_ * 4 + i) * PADW + quad * 4] = *(const uint2*)pk;
    }
    __syncthreads();
    const int pl = t >> 2, q = t & 3;
    u16* dst = xt + ((size_t)b * HW + p0 + pl) * NC + c0;
    #pragma unroll
    for (int s = 0; s < 2; ++s) {
        const int ch8 = q + s * 4;                 // 16B chunk (8 ch)
        const uint2 lo = *(const uint2*)&tile[pl * PADW + ch8 * 8];
        const uint2 hi = *(const uint2*)&tile[pl * PADW + ch8 * 8 + 4];
        const uint4 o4 = {lo.x, lo.y, hi.x, hi.y};
        *(uint4*)(dst + ch8 * 8) = o4;
    }
}

// ---------------- fold: reduce partials -> mu/rs, fold IN into weights/bias ----------------
// we[b][o][c] = w[o][c]*rs[b][c] (bf16), be[b][o] = bias[o] - sum_c w[o][c]*mu[b][c]*rs[b][c]
__global__ __launch_bounds__(256) void fold_kernel(
    const float* __restrict__ w, const float* __restrict__ bias,
    const float* __restrict__ ps, const float* __restrict__ pq, int P,
    u16* __restrict__ we, float* __restrict__ be)
{
    const int b = blockIdx.y, oc = blockIdx.x * 64;
    __shared__ float mu[NC], rs[NC];
    __shared__ __align__(16) float wt[64 * NC];
    const int t = threadIdx.x;
    {
        float s1 = 0.f, s2 = 0.f;
        const float* pp = ps + (size_t)b * P * NC + t;
        const float* qq = pq + (size_t)b * P * NC + t;
        for (int i = 0; i < P; ++i) { s1 += pp[(size_t)i * NC]; s2 += qq[(size_t)i * NC]; }
        const float m = s1 * (1.0f / HW);
        mu[t] = m;
        rs[t] = rsqrtf(s2 * (1.0f / HW) - m * m + 1e-5f);
    }
    #pragma unroll
    for (int i = 0; i < 16; ++i)
        *(float4*)&wt[i*1024 + t*4] = *(const float4*)&w[(size_t)oc*NC + i*1024 + t*4];
    __syncthreads();
    const int o = oc + (t >> 2), q = t & 3;
    const float* wrow = &wt[(t >> 2) * NC];
    u16* werow = we + ((size_t)b * NC + o) * NC;
    float bacc = 0.f;
    for (int cc = 0; cc < 8; ++cc) {
        alignas(16) u16 pk[8];
        #pragma unroll
        for (int jj = 0; jj < 8; ++jj) {
            const int c = q*64 + cc*8 + jj;
            const float wv = wrow[c];
            bacc -= wv * mu[c] * rs[c];
            pk[jj] = bf16bits(wv * rs[c]);
        }
        *(uint4*)(werow + q*64 + cc*8) = *(const uint4*)pk;
    }
    bacc += __shfl_xor(bacc, 1, 64);
    bacc += __shfl_xor(bacc, 2, 64);
    if (q == 0) be[b*NC + o] = bias[o] + bacc;
}

// ---------------- fused GEMM: 128 pixels x 256 outputs, 8 waves, 2-phase dbuf pipeline ----------------
// STAGE1: D[p][o] = relu(xt[p][:] . w1e[o][:] + b1e[o]) -> ht[b][p][o] bf16, + h col-sum partials
// STAGE2: D[o][p] = relu(w2e[o][:] . ht[p][:] + b2e[o]) -> out[b][o][p] fp32 (native NCHW)
template<int STAGE>
__global__ __launch_bounds__(512, 4) void gemm_kernel(
    const u16* __restrict__ pixM,   // pixel matrix [B*HW][NC] (xt or ht)
    const u16* __restrict__ wMat,   // folded weights [B][NC][NC]
    const float* __restrict__ biasE,// [B][NC]
    u16* __restrict__ outB,         // stage1: ht
    float* __restrict__ outF,       // stage2: out
    float* __restrict__ hps, float* __restrict__ hpq)  // stage1 partials [b][ptile][o]
{
    __shared__ __align__(16) u16 ldsP[2][128 * 32];   // pixel slab:  128 rows x 32 bf16 (8 KB ea)
    __shared__ __align__(16) u16 ldsW[2][256 * 32];   // weight slab: 256 rows x 32 bf16 (16 KB ea)

    const int b  = blockIdx.y;
    const int p0 = blockIdx.x * 128;
    const int tid = threadIdx.x;
    const int lane = tid & 63, wid = tid >> 6;        // 8 waves
    const int l15 = lane & 15, l4 = lane >> 4;
    const int wp = wid >> 2, wo = wid & 3;            // pixel-half, output-quarter

    const u16* gP = pixM + ((size_t)b * HW + p0) * NC;
    const u16* gW = wMat + (size_t)b * NC * NC;

    // staging constants: wave wid covers 16 rows per 8KB round; lane -> row base + (lane>>2), phys slot lane&3
    const int rin = lane >> 2;
    const int prow  = wid * 16 + rin;                 // pixel row 0..127
    const int wrow0 = wid * 16 + rin;                 // weight rows 0..127
    const int wrow1 = 128 + wid * 16 + rin;           // weight rows 128..255
    const int psl  = ((lane & 3) ^ prow  ^ (prow  >> 2)) & 3;
    const int wsl0 = ((lane & 3) ^ wrow0 ^ (wrow0 >> 2)) & 3;
    const int wsl1 = ((lane & 3) ^ wrow1 ^ (wrow1 >> 2)) & 3;

    f32x4 acc[4][4];
    #pragma unroll
    for (int i = 0; i < 4; ++i)
        #pragma unroll
        for (int j = 0; j < 4; ++j)
            acc[i][j] = (f32x4){0.f, 0.f, 0.f, 0.f};

    auto stage = [&](int ks, int buf) {
        const int k0 = ks * 32;
        gload16(gW + (size_t)wrow0 * NC + k0 + wsl0 * 8, (char*)ldsW[buf] + wid * 1024);
        gload16(gW + (size_t)wrow1 * NC + k0 + wsl1 * 8, (char*)ldsW[buf] + 8192 + wid * 1024);
        gload16(gP + (size_t)prow  * NC + k0 + psl  * 8, (char*)ldsP[buf] + wid * 1024);
    };

    stage(0, 0);
    __syncthreads();
    for (int ks = 0; ks < 8; ++ks) {
        const int cur = ks & 1;
        if (ks < 7) stage(ks + 1, cur ^ 1);           // prefetch overlaps this step's compute

        const u16* sA; const u16* sB; int aOff, bOff;
        if constexpr (STAGE == 1) { sA = ldsP[cur]; aOff = wp * 64; sB = ldsW[cur]; bOff = wo * 64; }
        else                      { sA = ldsW[cur]; aOff = wo * 64; sB = ldsP[cur]; bOff = wp * 64; }

        frag_ab a[4];
        #pragma unroll
        for (int mi = 0; mi < 4; ++mi)
            a[mi] = read_frag(sA, aOff + 16*mi + l15, l4);
        #pragma unroll
        for (int ni = 0; ni < 4; ++ni) {
            const frag_ab bfr = read_frag(sB, bOff + 16*ni + l15, l4);
            #pragma unroll
            for (int mi = 0; mi < 4; ++mi)
                acc[mi][ni] = __builtin_amdgcn_mfma_f32_16x16x32_bf16(a[mi], bfr, acc[mi][ni], 0, 0, 0);
        }
        __syncthreads();                              // drains prefetch + guards dbuf overwrite
    }

    if constexpr (STAGE == 1) {
        __shared__ float red1[2][4][64], red2[2][4][64];
        u16* htp = outB + ((size_t)b * HW + p0 + wp * 64) * NC + wo * 64;
        #pragma unroll
        for (int ni = 0; ni < 4; ++ni) {
            const int ocol = wo * 64 + 16*ni + l15;
            const float bn = biasE[b*NC + ocol];
            float s1 = 0.f, s2 = 0.f;
            #pragma unroll
            for (int mi = 0; mi < 4; ++mi) {
                #pragma unroll
                for (int r = 0; r < 4; ++r) {
                    const float v = fmaxf(acc[mi][ni][r] + bn, 0.f);
                    s1 += v; s2 += v * v;
                    htp[(size_t)(16*mi + l4*4 + r) * NC + 16*ni + l15] = bf16bits(v);
                }
            }
            s1 += __shfl_xor(s1, 16, 64); s1 += __shfl_xor(s1, 32, 64);
            s2 += __shfl_xor(s2, 16, 64); s2 += __shfl_xor(s2, 32, 64);
            if (l4 == 0) { red1[wp][wo][ni*16 + l15] = s1; red2[wp][wo][ni*16 + l15] = s2; }
        }
        __syncthreads();
        if (tid < 256) {
            const int o = tid;
            const float s1 = red1[0][o >> 6][o & 63] + red1[1][o >> 6][o & 63];
            const float s2 = red2[0][o >> 6][o & 63] + red2[1][o >> 6][o & 63];
            hps[((size_t)b * 128 + blockIdx.x) * NC + o] = s1;
            hpq[((size_t)b * 128 + blockIdx.x) * NC + o] = s2;
        }
    } else {
        float* op = outF + ((size_t)b * NC + wo * 64) * HW + p0 + wp * 64;
        #pragma unroll
        for (int mi = 0; mi < 4; ++mi) {
            #pragma unroll
            for (int r = 0; r < 4; ++r) {
                const int orow = 16*mi + l4*4 + r;
                const float bm = biasE[b*NC + wo*64 + orow];
                #pragma unroll
                for (int ni = 0; ni < 4; ++ni)
                    op[(size_t)orow * HW + 16*ni + l15] = fmaxf(acc[mi][ni][r] + bm, 0.f);
            }
        }
    }
}

extern "C" void kernel_launch(void* const* d_in, const int* in_sizes, int n_in,
                              void* d_out, int out_size, void* d_ws, size_t ws_size,
                              hipStream_t stream)
{
    (void)in_sizes; (void)n_in; (void)out_size;
    const float* x  = (const float*)d_in[0];
    const float* w1 = (const float*)d_in[1];
    const float* b1 = (const float*)d_in[2];
    const float* w2 = (const float*)d_in[3];
    const float* b2 = (const float*)d_in[4];
    float* out = (float*)d_out;

    // scratch carved out of d_out (268 MB): everything here is dead before gemm<2> overwrites it
    char* od = (char*)d_out;
    u16*   xt  = (u16*)od;                        // 134,217,728 B
    float* xps = (float*)(od + 134217728);        //   4,194,304 (16*256*256 f32)
    float* xpq = (float*)(od + 138412032);        //   4,194,304
    float* hps = (float*)(od + 142606336);        //   2,097,152 (16*128*256 f32)
    float* hpq = (float*)(od + 144703488);        //   2,097,152

    char* ws = (char*)d_ws;
    const size_t NEED = 138444800;
    if (ws_size < NEED) return;                   // loud failure instead of corruption
    u16*   ht  = (u16*)(ws);                      // 134,217,728
    u16*   w1e = (u16*)(ws + 134217728);          //   2,097,152
    u16*   w2e = (u16*)(ws + 136314880);          //   2,097,152
    float* b1e = (float*)(ws + 138412032);        //      16,384
    float* b2e = (float*)(ws + 138428416);        //      16,384

    transpose_stats_kernel<<<dim3(HW/64, NC/64, 16), 256, 0, stream>>>(x, xt, xps, xpq);
    fold_kernel<<<dim3(4, 16), 256, 0, stream>>>(w1, b1, xps, xpq, 256, w1e, b1e);
    gemm_kernel<1><<<dim3(HW/128, 16), 512, 0, stream>>>(xt, w1e, b1e, ht, nullptr, hps, hpq);
    fold_kernel<<<dim3(4, 16), 256, 0, stream>>>(w2, b2, hps, hpq, 128, w2e, b2e);
    gemm_kernel<2><<<dim3(HW/128, 16), 512, 0, stream>>>(ht, w2e, b2e, nullptr, out, nullptr, nullptr);
}